// Round 7
// baseline (297.309 us; speedup 1.0000x reference)
//
#include <hip/hip_runtime.h>
#include <stdint.h>
#include <stddef.h>

typedef __bf16 bf16;
typedef __attribute__((ext_vector_type(8))) __bf16 bf16x8;
typedef __attribute__((ext_vector_type(4))) __bf16 bf16x4;
typedef __attribute__((ext_vector_type(4))) float f32x4;
typedef __attribute__((ext_vector_type(4))) float float4v;

#define BATCH 4
#define SEQ   2048
#define EMB   1024
#define NH    16
#define HD    64
#define F3    3072   // 3*EMB

#define MFMA16(a, b, c) __builtin_amdgcn_mfma_f32_16x16x32_bf16((a), (b), (c), 0, 0, 0)

// async global->LDS, 16B per lane. lds ptr must be wave-uniform; lane i lands at l + i*16B.
__device__ __forceinline__ void gload_lds16(const bf16* g, bf16* l) {
  __builtin_amdgcn_global_load_lds(
      (const __attribute__((address_space(1))) uint32_t*)g,
      (__attribute__((address_space(3))) uint32_t*)l, 16, 0, 0);
}

// ---------------------------------------------------------------------------
// RoPE table: cos/sin[pos][d1] for pos<2048, d1<32, f32 (ref keeps f32).
// ---------------------------------------------------------------------------
__global__ __launch_bounds__(256) void rope_table(float* __restrict__ cosT,
                                                  float* __restrict__ sinT) {
  int idx = blockIdx.x * 256 + threadIdx.x;   // 65536
  int pos = idx >> 5, d1 = idx & 31;
  float inv = powf(10000.0f, -(float)(2 * d1) / 64.0f);
  float th = (float)pos * inv;
  cosT[idx] = cosf(th);
  sinT[idx] = sinf(th);
}

// ---------------------------------------------------------------------------
// Convert f32 -> bf16. n4 = count/4.
// ---------------------------------------------------------------------------
__global__ __launch_bounds__(256) void convert_bf16(const float* __restrict__ src,
                                                    bf16* __restrict__ dst, int n4) {
  int i = blockIdx.x * 256 + threadIdx.x;
  if (i >= n4) return;
  float4v v = ((const float4v*)src)[i];
  bf16x4 o;
#pragma unroll
  for (int k = 0; k < 4; ++k) o[k] = (bf16)v[k];
  ((bf16x4*)dst)[i] = o;
}

// ---------------------------------------------------------------------------
// Transpose + convert: in [R][C] f32 -> out [C][R] bf16.
// ---------------------------------------------------------------------------
__global__ __launch_bounds__(256) void transpose_f32_bf16(const float* __restrict__ in,
                                                          bf16* __restrict__ out,
                                                          int R, int C) {
  __shared__ bf16 tile[32][33];
  const int tx = threadIdx.x & 31;
  const int ty = threadIdx.x >> 5;  // 0..7
  const int c0 = blockIdx.x * 32, r0 = blockIdx.y * 32;
#pragma unroll
  for (int kk = 0; kk < 4; ++kk) {
    int r = ty + kk * 8;
    tile[r][tx] = (bf16)in[(size_t)(r0 + r) * C + c0 + tx];
  }
  __syncthreads();
#pragma unroll
  for (int kk = 0; kk < 4; ++kk) {
    int r = ty + kk * 8;
    out[(size_t)(c0 + r) * R + r0 + tx] = tile[tx][r];
  }
}

// ---------------------------------------------------------------------------
// QKV GEMM + bias + RoPE + scatter (unchanged — known-good).
// ---------------------------------------------------------------------------
__global__ __launch_bounds__(256) void qkv_rope_kernel(
    const bf16* __restrict__ x, const bf16* __restrict__ wT,
    const float* __restrict__ bias, bf16* __restrict__ qo, bf16* __restrict__ ko,
    bf16* __restrict__ vo, const float* __restrict__ cosT,
    const float* __restrict__ sinT) {
  __shared__ __align__(16) bf16 As[128 * 32];
  __shared__ __align__(16) bf16 Bs[128 * 32];
  const int tid = threadIdx.x;
  const int w = tid >> 6, lane = tid & 63;
  const int lhi = lane >> 4, llo = lane & 15;
  const int wr = w >> 1, wc = w & 1;
  const int row_a0 = blockIdx.y * 128;
  const int row_b0 = blockIdx.x * 128;

  f32x4 acc[4][4];
#pragma unroll
  for (int i = 0; i < 4; ++i)
#pragma unroll
    for (int j = 0; j < 4; ++j) acc[i][j] = (f32x4){0.f, 0.f, 0.f, 0.f};

  for (int k0 = 0; k0 < EMB; k0 += 32) {
#pragma unroll
    for (int c = 0; c < 2; ++c) {
      int chunk = w * 2 + c;
      int gl = chunk * 64 + lane;
      int row = gl >> 2, kk = (gl & 3) << 3;
      gload_lds16(x + (size_t)(row_a0 + row) * EMB + k0 + kk, &As[chunk * 512]);
      gload_lds16(wT + (size_t)(row_b0 + row) * EMB + k0 + kk, &Bs[chunk * 512]);
    }
    __syncthreads();
    bf16x8 a[4], b[4];
#pragma unroll
    for (int i = 0; i < 4; ++i)
      a[i] = *(const bf16x8*)&As[(wr * 64 + i * 16 + llo) * 32 + lhi * 8];
#pragma unroll
    for (int j = 0; j < 4; ++j)
      b[j] = *(const bf16x8*)&Bs[(wc * 64 + j * 16 + llo) * 32 + lhi * 8];
#pragma unroll
    for (int i = 0; i < 4; ++i)
#pragma unroll
      for (int j = 0; j < 4; ++j) acc[i][j] = MFMA16(a[i], b[j], acc[i][j]);
    __syncthreads();
  }

  const int f0 = row_b0 + wc * 64;      // wave col base, 64-aligned
  const int part = f0 >> 10;            // 0=Q 1=K 2=V
  const int hh = (f0 & 1023) >> 6;      // head
  const int m_base = row_a0 + wr * 64;

  float bvals[4];
#pragma unroll
  for (int j = 0; j < 4; ++j) bvals[j] = bias[f0 + j * 16 + llo];

  if (part == 2) {
#pragma unroll
    for (int i = 0; i < 4; ++i) {
      int m0 = m_base + i * 16 + lhi * 4;
      int bb = m0 >> 11, pos0 = m0 & 2047;
#pragma unroll
      for (int j = 0; j < 4; ++j) {
        int dd = j * 16 + llo;
        bf16x4 pk;
#pragma unroll
        for (int r = 0; r < 4; ++r) pk[r] = (bf16)(acc[i][j][r] + bvals[j]);
        *(bf16x4*)(vo + ((size_t)(bb * NH + hh) * HD + dd) * SEQ + pos0) = pk;
      }
    }
  } else {
    bf16* dst = (part == 0) ? qo : ko;
    const float qs = (part == 0) ? 0.125f : 1.0f;  // fold 1/sqrt(64) into Q (exact pow2)
#pragma unroll
    for (int i = 0; i < 4; ++i) {
#pragma unroll
      for (int r = 0; r < 4; ++r) {
        int m = m_base + i * 16 + lhi * 4 + r;
        int bb = m >> 11, pos = m & 2047;
        size_t base = ((size_t)(bb * NH + hh) * SEQ + pos) * HD;
#pragma unroll
        for (int j = 0; j < 2; ++j) {
          int d1 = j * 16 + llo;
          float x1 = acc[i][j][r] + bvals[j];
          float x2 = acc[i][j + 2][r] + bvals[j + 2];
          float cth = cosT[pos * 32 + d1];
          float sth = sinT[pos * 32 + d1];
          dst[base + d1] = (bf16)((x1 * cth - x2 * sth) * qs);
          dst[base + d1 + 32] = (bf16)((x2 * cth + x1 * sth) * qs);
        }
      }
    }
  }
}

// ---------------------------------------------------------------------------
// Flash attention v5: 256-thread blocks (4 waves), 64 q-rows PER WAVE
// (256 q/block), BK=64, double-buffered K/V, one barrier per tile.
// Fat waves amortize K/V fragment reads: 32 KB LDS per wave-tile for 64 q
// (was 24 KB for 32 q) -> 33% less LDS traffic per FLOP.
// Transposed-score MFMA (S^T = K·Q^T) -> packed b64 P writes.
// Tokens processed in two 32-token halves (th) to cap VGPRs (~160).
// LDS 64 KB: [0,16384 ents) Q-staging, overlaid by per-wave P (w*4096;
//   wave w's P covers exactly its own Q rows -> no barrier needed);
//   [16384,24576) K dbuf; [24576,32768) V^T dbuf. XOR-swizzled.
// Grid 512 = 2 blocks/CU. XCD remap keeps each head's K/V on one XCD.
// ---------------------------------------------------------------------------
__global__ __launch_bounds__(256) void attn_kernel(const bf16* __restrict__ q,
                                                   const bf16* __restrict__ k,
                                                   const bf16* __restrict__ vT,
                                                   bf16* __restrict__ o) {
  __shared__ __align__(16) bf16 smem[32768];
  bf16* Qs = smem;

  const int tid = threadIdx.x, w = tid >> 6, lane = tid & 63;
  const int lhi = lane >> 4, llo = lane & 15;
  const int l7 = llo & 7;
  const int bidx = blockIdx.x;
  const int vblk = (bidx & 7) * 64 + (bidx >> 3);  // XCD-contiguous remap (512 blocks)
  const int qt = vblk & 7, bh = vblk >> 3;         // 8 q-tiles of 256, bh in [0,64)
  const bf16* qbase = q + (size_t)bh * SEQ * HD + qt * 256 * HD;
  const bf16* kbase = k + (size_t)bh * SEQ * HD;
  const bf16* vbase = vT + (size_t)bh * HD * SEQ;
  bf16* Pw = smem + w * 4096;   // wave-private 64q x 64tok P (overlays own Q rows)

  const int rowc = lane >> 3;                     // row within 8-row chunk
  const int sw8 = (lane & 7) ^ rowc;              // staging XOR swizzle (16B granules)

  // stage Q (8 chunks/wave = own 64 rows) + K0/V0 (2 chunks each per wave)
#pragma unroll
  for (int c = 0; c < 8; ++c) {
    int chunk = w * 8 + c;
    int row = chunk * 8 + rowc;
    gload_lds16(qbase + (size_t)row * HD + sw8 * 8, &Qs[chunk * 512]);
  }
#pragma unroll
  for (int c = 0; c < 2; ++c) {
    int chunk = w * 2 + c;
    int row = chunk * 8 + rowc;
    gload_lds16(kbase + (size_t)row * HD + sw8 * 8, &smem[16384 + chunk * 512]);
    gload_lds16(vbase + (size_t)row * SEQ + sw8 * 8, &smem[24576 + chunk * 512]);
  }
  __syncthreads();

  // Q fragments: wave's own 64 q rows (4 groups of 16), both 32-dim halves.
  bf16x8 qf[4][2];
#pragma unroll
  for (int qi = 0; qi < 4; ++qi)
#pragma unroll
    for (int kc = 0; kc < 2; ++kc)
      qf[qi][kc] = *(const bf16x8*)&Qs[(w * 64 + qi * 16 + llo) * 64 +
                                       (((kc * 4 + lhi) ^ l7) * 8)];
  // no barrier: wave w only overwrites (P) the Q rows it alone just read.

  float rsum[4] = {0.f, 0.f, 0.f, 0.f};
  f32x4 oacc[4][4];
#pragma unroll
  for (int qi = 0; qi < 4; ++qi)
#pragma unroll
    for (int jd = 0; jd < 4; ++jd) oacc[qi][jd] = (f32x4){0.f, 0.f, 0.f, 0.f};

  for (int kb = 0; kb < 32; ++kb) {
    bf16* Kc = smem + 16384 + (kb & 1) * 4096;
    bf16* Vc = smem + 24576 + (kb & 1) * 4096;
    // prefetch next tile into alt buffers (lands during this tile's compute)
    if (kb < 31) {
      bf16* Kn = smem + 16384 + ((kb + 1) & 1) * 4096;
      bf16* Vn = smem + 24576 + ((kb + 1) & 1) * 4096;
      int kpos = (kb + 1) * 64;
#pragma unroll
      for (int c = 0; c < 2; ++c) {
        int chunk = w * 2 + c;
        int row = chunk * 8 + rowc;
        gload_lds16(kbase + (size_t)(kpos + row) * HD + sw8 * 8, &Kn[chunk * 512]);
        gload_lds16(vbase + (size_t)row * SEQ + kpos + sw8 * 8, &Vn[chunk * 512]);
      }
    }
    // S^T = K Q^T in two 32-token halves; exp + packed P write per half.
#pragma unroll
    for (int th = 0; th < 2; ++th) {
      f32x4 st[2][4];
#pragma unroll
      for (int t2 = 0; t2 < 2; ++t2)
#pragma unroll
        for (int qi = 0; qi < 4; ++qi) st[t2][qi] = (f32x4){0.f, 0.f, 0.f, 0.f};
#pragma unroll
      for (int kc = 0; kc < 2; ++kc) {
        bf16x8 kfr[2];
#pragma unroll
        for (int t2 = 0; t2 < 2; ++t2)
          kfr[t2] = *(const bf16x8*)&Kc[((th * 2 + t2) * 16 + llo) * 64 +
                                        (((kc * 4 + lhi) ^ l7) * 8)];
#pragma unroll
        for (int t2 = 0; t2 < 2; ++t2)
#pragma unroll
          for (int qi = 0; qi < 4; ++qi)
            st[t2][qi] = MFMA16(kfr[t2], qf[qi][kc], st[t2][qi]);
      }
      // lane holds 4 consecutive tokens (th*32+t2*16+lhi*4+r) of q-row qi*16+llo
#pragma unroll
      for (int t2 = 0; t2 < 2; ++t2) {
#pragma unroll
        for (int qi = 0; qi < 4; ++qi) {
          bf16x4 pk;
          float a = 0.f;
#pragma unroll
          for (int r = 0; r < 4; ++r) {
            float p = __expf(st[t2][qi][r]);
            pk[r] = (bf16)p;
            a += p;
          }
          rsum[qi] += a;
          int sg = (th * 8 + t2 * 4 + lhi) ^ (l7 << 1);   // granule swizzle
          *(bf16x4*)&Pw[(qi * 16 + llo) * 64 + sg * 4] = pk;
        }
      }
    }
    // O += P V  (P A-operand from q-major LDS; V^T rows token-contiguous)
#pragma unroll
    for (int kc = 0; kc < 2; ++kc) {
      bf16x8 af[4], bv[4];
      int xg = ((kc * 4 + lhi) ^ l7) * 8;
#pragma unroll
      for (int qi = 0; qi < 4; ++qi)
        af[qi] = *(const bf16x8*)&Pw[(qi * 16 + llo) * 64 + xg];
#pragma unroll
      for (int jd = 0; jd < 4; ++jd)
        bv[jd] = *(const bf16x8*)&Vc[(jd * 16 + llo) * 64 + xg];
#pragma unroll
      for (int qi = 0; qi < 4; ++qi)
#pragma unroll
        for (int jd = 0; jd < 4; ++jd)
          oacc[qi][jd] = MFMA16(af[qi], bv[jd], oacc[qi][jd]);
    }
    __syncthreads();  // end of tile: prefetch landed + guards buffer reuse
  }

  // epilogue: lane holds rsum for q=qi*16+llo over its 16 tokens; reduce over
  // lhi lanes (xor 16,32), redistribute to oacc row owners via shfl, write.
  const int bb = bh >> 4, hh = bh & 15;
#pragma unroll
  for (int qi = 0; qi < 4; ++qi) {
    float t = rsum[qi];
    t += __shfl_xor(t, 16);
    t += __shfl_xor(t, 32);
#pragma unroll
    for (int r = 0; r < 4; ++r) {
      float l = __shfl(t, lhi * 4 + r);   // total for q-row qi*16+lhi*4+r
      float inv = 1.0f / l;
      int pos = qt * 256 + w * 64 + qi * 16 + lhi * 4 + r;
      size_t base = ((size_t)bb * SEQ + pos) * EMB + hh * HD;
#pragma unroll
      for (int jd = 0; jd < 4; ++jd)
        o[base + jd * 16 + llo] = (bf16)(oacc[qi][jd][r] * inv);
    }
  }
}

// ---------------------------------------------------------------------------
// Output projection (unchanged): A = ow bf16, BT = woT bf16, + bo, out f32.
// ---------------------------------------------------------------------------
__global__ __launch_bounds__(256) void outproj_kernel(const bf16* __restrict__ a_in,
                                                      const bf16* __restrict__ wT,
                                                      const float* __restrict__ bo,
                                                      float* __restrict__ out) {
  __shared__ __align__(16) bf16 As[128 * 32];
  __shared__ __align__(16) bf16 Bs[128 * 32];
  const int tid = threadIdx.x;
  const int w = tid >> 6, lane = tid & 63;
  const int lhi = lane >> 4, llo = lane & 15;
  const int wr = w >> 1, wc = w & 1;
  const int row_a0 = blockIdx.y * 128;
  const int row_b0 = blockIdx.x * 128;

  f32x4 acc[4][4];
#pragma unroll
  for (int i = 0; i < 4; ++i)
#pragma unroll
    for (int j = 0; j < 4; ++j) acc[i][j] = (f32x4){0.f, 0.f, 0.f, 0.f};

  for (int k0 = 0; k0 < EMB; k0 += 32) {
#pragma unroll
    for (int c = 0; c < 2; ++c) {
      int chunk = w * 2 + c;
      int gl = chunk * 64 + lane;
      int row = gl >> 2, kk = (gl & 3) << 3;
      gload_lds16(a_in + (size_t)(row_a0 + row) * EMB + k0 + kk, &As[chunk * 512]);
      gload_lds16(wT + (size_t)(row_b0 + row) * EMB + k0 + kk, &Bs[chunk * 512]);
    }
    __syncthreads();
    bf16x8 a[4], b[4];
#pragma unroll
    for (int i = 0; i < 4; ++i)
      a[i] = *(const bf16x8*)&As[(wr * 64 + i * 16 + llo) * 32 + lhi * 8];
#pragma unroll
    for (int j = 0; j < 4; ++j)
      b[j] = *(const bf16x8*)&Bs[(wc * 64 + j * 16 + llo) * 32 + lhi * 8];
#pragma unroll
    for (int i = 0; i < 4; ++i)
#pragma unroll
      for (int j = 0; j < 4; ++j) acc[i][j] = MFMA16(a[i], b[j], acc[i][j]);
    __syncthreads();
  }

  const int col0 = row_b0 + wc * 64;
  const int m_base = row_a0 + wr * 64;
  float bvals[4];
#pragma unroll
  for (int j = 0; j < 4; ++j) bvals[j] = bo[col0 + j * 16 + llo];
#pragma unroll
  for (int i = 0; i < 4; ++i) {
#pragma unroll
    for (int r = 0; r < 4; ++r) {
      int m = m_base + i * 16 + lhi * 4 + r;
#pragma unroll
      for (int j = 0; j < 4; ++j)
        out[(size_t)m * EMB + col0 + j * 16 + llo] = acc[i][j][r] + bvals[j];
    }
  }
}

// ---------------------------------------------------------------------------
// Workspace layout (<= 64 MiB used):
//   [0, 16M)   qw [b,h,s,d] bf16   (later woT @0..2M after attn)
//   [16M,32M)  kw;  [32M,48M) vw [b,h,d,s]
//   [48M,64M)  phase1-2: wqkvT (6M) + cosT/sinT; phase3-4: ow bf16 (16M)
// d_out (33.5 MB f32) doubles as xb scratch (16.8 MB bf16) in phases 1-2.
// ---------------------------------------------------------------------------
extern "C" void kernel_launch(void* const* d_in, const int* in_sizes, int n_in,
                              void* d_out, int out_size, void* d_ws, size_t ws_size,
                              hipStream_t stream) {
  const float* x_raw = (const float*)d_in[0];
  const float* wqkv_raw = (const float*)d_in[1];
  const float* bqkv = (const float*)d_in[2];
  const float* wo_raw = (const float*)d_in[3];
  const float* bo = (const float*)d_in[4];
  float* out = (float*)d_out;

  char* ws = (char*)d_ws;
  bf16* qw = (bf16*)(ws);                       // 16 MiB
  bf16* kw = (bf16*)(ws + 16777216);            // 16 MiB
  bf16* vw = (bf16*)(ws + 33554432);            // 16 MiB
  bf16* wqkvT = (bf16*)(ws + 50331648);         // 6 MiB (phase 1-2)
  float* cosT = (float*)(ws + 56623104);        // 256 KiB (phase 1-2)
  float* sinT = (float*)(ws + 56885248);        // 256 KiB (phase 1-2)
  bf16* ow = (bf16*)(ws + 50331648);            // 16 MiB (phase 3-4, overlays above)
  bf16* woT = (bf16*)(ws);                      // 2 MiB (phase 3.5-4, overlays qw)
  bf16* xb = (bf16*)d_out;                      // 16.8 MiB scratch in d_out (phase 1-2)

  rope_table<<<256, 256, 0, stream>>>(cosT, sinT);
  convert_bf16<<<(BATCH * SEQ * EMB / 4 + 255) / 256, 256, 0, stream>>>(
      x_raw, xb, BATCH * SEQ * EMB / 4);
  transpose_f32_bf16<<<dim3(F3 / 32, EMB / 32), 256, 0, stream>>>(wqkv_raw, wqkvT, EMB, F3);

  qkv_rope_kernel<<<dim3(F3 / 128, (BATCH * SEQ) / 128), 256, 0, stream>>>(
      xb, wqkvT, bqkv, qw, kw, vw, cosT, sinT);
  attn_kernel<<<dim3(BATCH * NH * (SEQ / 256)), 256, 0, stream>>>(qw, kw, vw, ow);

  transpose_f32_bf16<<<dim3(EMB / 32, EMB / 32), 256, 0, stream>>>(wo_raw, woT, EMB, EMB);
  outproj_kernel<<<dim3(EMB / 128, (BATCH * SEQ) / 128), 256, 0, stream>>>(
      ow, woT, bo, out);
}